// Round 1
// baseline (550.849 us; speedup 1.0000x reference)
//
#include <hip/hip_runtime.h>

// B=2, L=S=2048, D_MODEL=1024, H=16, D_HEAD=64
// d_out = [out: 2*2048*1024 f32][A: 2*16*2048*2048 f32]

typedef __attribute__((ext_vector_type(8))) __bf16 bf16x8;
typedef __attribute__((ext_vector_type(4))) float f32x4;

__device__ __forceinline__ unsigned int f2bf_u(float f) {
  unsigned int u = __float_as_uint(f);
  return (u + 0x7FFFu + ((u >> 16) & 1u)) >> 16;  // RNE
}
__device__ __forceinline__ float bf2f(unsigned int h) {
  return __uint_as_float(h << 16);
}
__device__ __forceinline__ unsigned int pack2(float lo, float hi) {
  return (f2bf_u(hi) << 16) | f2bf_u(lo);
}
__device__ __forceinline__ f32x4 mfma16(bf16x8 a, bf16x8 b, f32x4 c) {
  return __builtin_amdgcn_mfma_f32_16x16x32_bf16(a, b, c, 0, 0, 0);
}

// ---------------------------------------------------------------- transpose
// W[1024 in][1024 out] f32  ->  WT[1024 out][1024 in] bf16
__global__ __launch_bounds__(256) void transpose_w(
    const float* __restrict__ W0, const float* __restrict__ W1,
    const float* __restrict__ W2, const float* __restrict__ W3,
    unsigned short* __restrict__ T0, unsigned short* __restrict__ T1,
    unsigned short* __restrict__ T2, unsigned short* __restrict__ T3) {
  const float* W; unsigned short* T;
  switch (blockIdx.z) {
    case 0: W = W0; T = T0; break;
    case 1: W = W1; T = T1; break;
    case 2: W = W2; T = T2; break;
    default: W = W3; T = T3; break;
  }
  __shared__ float tile[32][33];
  const int tx = threadIdx.x, ty = threadIdx.y;       // 32 x 8
  const int i0 = blockIdx.x * 32, o0 = blockIdx.y * 32;
  #pragma unroll
  for (int r = 0; r < 4; ++r)
    tile[ty + 8 * r][tx] = W[(size_t)(i0 + ty + 8 * r) * 1024 + o0 + tx];
  __syncthreads();
  #pragma unroll
  for (int r = 0; r < 4; ++r)
    T[(size_t)(o0 + ty + 8 * r) * 1024 + i0 + tx] =
        (unsigned short)f2bf_u(tile[tx][ty + 8 * r]);
}

// ---------------------------------------------------------------- GEMM 128x128
// C[M,N] = A[M,K] * BT[N,K]^T + bias ; A f32 (converted) or bf16 ; C f32 or bf16
template <bool A_BF16, bool OUT_F32>
__global__ __launch_bounds__(256) void gemm128(
    const void* __restrict__ Ap, const unsigned short* __restrict__ BT,
    const float* __restrict__ bias, void* __restrict__ Cp,
    int M, int N, int K) {
  __shared__ unsigned short As[128][32];
  __shared__ unsigned short Bs[128][32];
  const int tid = threadIdx.x;
  const int lane = tid & 63, wid = tid >> 6;
  const int l15 = lane & 15, l4 = lane >> 4;
  const int m0 = blockIdx.x * 128, n0 = blockIdx.y * 128;
  const int wr = wid >> 1, wc = wid & 1;

  f32x4 acc[4][4];
  #pragma unroll
  for (int i = 0; i < 4; ++i)
    #pragma unroll
    for (int j = 0; j < 4; ++j) acc[i][j] = (f32x4){0.f, 0.f, 0.f, 0.f};

  const int nk = K >> 5;
  for (int kt = 0; kt < nk; ++kt) {
    if (tid < 128) {  // waves 0-1: stage A (one row of 32 elems per thread)
      const int row = tid;
      uint4* dst = (uint4*)&As[row][0];
      if constexpr (A_BF16) {
        const uint4* src = (const uint4*)((const unsigned short*)Ap +
                                          (size_t)(m0 + row) * K + kt * 32);
        #pragma unroll
        for (int c = 0; c < 4; ++c) dst[c] = src[c];
      } else {
        const float4* src = (const float4*)((const float*)Ap +
                                            (size_t)(m0 + row) * K + kt * 32);
        #pragma unroll
        for (int c = 0; c < 4; ++c) {
          float4 f0 = src[2 * c], f1 = src[2 * c + 1];
          uint4 o;
          o.x = pack2(f0.x, f0.y);
          o.y = pack2(f0.z, f0.w);
          o.z = pack2(f1.x, f1.y);
          o.w = pack2(f1.z, f1.w);
          dst[c] = o;
        }
      }
    } else {          // waves 2-3: stage B
      const int row = tid - 128;
      const uint4* src = (const uint4*)(BT + (size_t)(n0 + row) * K + kt * 32);
      uint4* dst = (uint4*)&Bs[row][0];
      #pragma unroll
      for (int c = 0; c < 4; ++c) dst[c] = src[c];
    }
    __syncthreads();
    bf16x8 af[4], bfr[4];
    #pragma unroll
    for (int i = 0; i < 4; ++i)
      af[i] = *(const bf16x8*)&As[wr * 64 + i * 16 + l15][l4 * 8];
    #pragma unroll
    for (int j = 0; j < 4; ++j)
      bfr[j] = *(const bf16x8*)&Bs[wc * 64 + j * 16 + l15][l4 * 8];
    #pragma unroll
    for (int i = 0; i < 4; ++i)
      #pragma unroll
      for (int j = 0; j < 4; ++j)
        acc[i][j] = mfma16(af[i], bfr[j], acc[i][j]);
    __syncthreads();
  }

  #pragma unroll
  for (int j = 0; j < 4; ++j) {
    const int col = n0 + wc * 64 + j * 16 + l15;
    const float bv = bias[col];
    #pragma unroll
    for (int i = 0; i < 4; ++i) {
      const int rowb = m0 + wr * 64 + i * 16 + l4 * 4;
      #pragma unroll
      for (int q = 0; q < 4; ++q) {
        const float v = acc[i][j][q] + bv;
        if constexpr (OUT_F32)
          ((float*)Cp)[(size_t)(rowb + q) * N + col] = v;
        else
          ((unsigned short*)Cp)[(size_t)(rowb + q) * N + col] =
              (unsigned short)f2bf_u(v);
      }
    }
  }
}

// ---------------------------------------------------------------- fused attention
// grid (L/32=64, B*H=32), block 512 (8 waves). Per WG: 32 q-rows, full S=2048.
// Scores register-resident (packed bf16, 64 u32/lane). Writes A (f32, d_out)
// and out_pre (bf16, ws).
__global__ __launch_bounds__(512) void attn_fused(
    const unsigned short* __restrict__ Q, const unsigned short* __restrict__ K,
    const unsigned short* __restrict__ V, float* __restrict__ Aout,
    unsigned short* __restrict__ OutPre) {
  union Smem {
    struct { unsigned short prob[32][136]; unsigned short vt[64][136]; } p;
    float pvred[2][4][16][64];
  };
  __shared__ Smem u;
  __shared__ float stats[8][32];
  __shared__ float mrow[32];
  __shared__ float lrow[32];

  const int tid = threadIdx.x;
  const int w = tid >> 6;
  const int lane = tid & 63;
  const int l15 = lane & 15;
  const int l4 = lane >> 4;
  const int bh = blockIdx.y;
  const int b = bh >> 4, h = bh & 15;
  const int m0 = blockIdx.x * 32;

  // Q fragments (A-operand): rows mf*16+l15, k-chunks of 8 at l4*8
  bf16x8 qf[2][2];
  {
    const unsigned short* Qb = Q + ((size_t)(b * 2048 + m0) << 10) + h * 64;
    #pragma unroll
    for (int mf = 0; mf < 2; ++mf)
      #pragma unroll
      for (int kc = 0; kc < 2; ++kc)
        qf[mf][kc] = *(const bf16x8*)(Qb + ((size_t)(mf * 16 + l15) << 10) +
                                      kc * 32 + l4 * 8);
  }

  const unsigned short* Kb = K + ((size_t)b << 21) + h * 64;
  unsigned int sc[64];   // packed bf16 scaled scores (lo=rows 0-15, hi=rows 16-31)
  float rmax[8];
  #pragma unroll
  for (int r = 0; r < 8; ++r) rmax[r] = -3.0e38f;

  // ---- phase 1: QK^T, keep scores in registers, track row max
  #pragma unroll
  for (int i = 0; i < 16; ++i) {
    const int s = i * 128 + w * 16 + l15;
    const unsigned short* kp = Kb + ((size_t)s << 10) + l4 * 8;
    bf16x8 k0 = *(const bf16x8*)kp;
    bf16x8 k1 = *(const bf16x8*)(kp + 32);
    f32x4 a0 = {0.f, 0.f, 0.f, 0.f}, a1 = {0.f, 0.f, 0.f, 0.f};
    a0 = mfma16(qf[0][0], k0, a0); a0 = mfma16(qf[0][1], k1, a0);
    a1 = mfma16(qf[1][0], k0, a1); a1 = mfma16(qf[1][1], k1, a1);
    #pragma unroll
    for (int j = 0; j < 4; ++j) {
      const unsigned int p = pack2(a0[j] * 0.125f, a1[j] * 0.125f);
      sc[i * 4 + j] = p;
      rmax[j]     = fmaxf(rmax[j],     bf2f(p & 0xffffu));
      rmax[4 + j] = fmaxf(rmax[4 + j], bf2f(p >> 16));
    }
  }
  #pragma unroll
  for (int r = 0; r < 8; ++r) {
    float v = rmax[r];
    v = fmaxf(v, __shfl_xor(v, 1));
    v = fmaxf(v, __shfl_xor(v, 2));
    v = fmaxf(v, __shfl_xor(v, 4));
    v = fmaxf(v, __shfl_xor(v, 8));
    rmax[r] = v;
  }
  if (l15 == 0) {
    #pragma unroll
    for (int j = 0; j < 4; ++j) {
      stats[w][l4 * 4 + j] = rmax[j];
      stats[w][16 + l4 * 4 + j] = rmax[4 + j];
    }
  }
  __syncthreads();
  if (tid < 32) {
    float m = stats[0][tid];
    #pragma unroll
    for (int ww = 1; ww < 8; ++ww) m = fmaxf(m, stats[ww][tid]);
    mrow[tid] = m;
  }
  __syncthreads();
  float mreg[8];
  #pragma unroll
  for (int j = 0; j < 4; ++j) {
    mreg[j] = mrow[l4 * 4 + j];
    mreg[4 + j] = mrow[16 + l4 * 4 + j];
  }
  float lsum[8];
  #pragma unroll
  for (int r = 0; r < 8; ++r) lsum[r] = 0.f;
  #pragma unroll
  for (int i = 0; i < 16; ++i) {
    #pragma unroll
    for (int j = 0; j < 4; ++j) {
      const unsigned int p = sc[i * 4 + j];
      lsum[j]     += __expf(bf2f(p & 0xffffu) - mreg[j]);
      lsum[4 + j] += __expf(bf2f(p >> 16)    - mreg[4 + j]);
    }
  }
  #pragma unroll
  for (int r = 0; r < 8; ++r) {
    float v = lsum[r];
    v += __shfl_xor(v, 1);
    v += __shfl_xor(v, 2);
    v += __shfl_xor(v, 4);
    v += __shfl_xor(v, 8);
    lsum[r] = v;
  }
  if (l15 == 0) {
    #pragma unroll
    for (int j = 0; j < 4; ++j) {
      stats[w][l4 * 4 + j] = lsum[j];
      stats[w][16 + l4 * 4 + j] = lsum[4 + j];
    }
  }
  __syncthreads();
  if (tid < 32) {
    float s = 0.f;
    #pragma unroll
    for (int ww = 0; ww < 8; ++ww) s += stats[ww][tid];
    lrow[tid] = 1.0f / s;
  }
  __syncthreads();
  float lreg[8];
  #pragma unroll
  for (int j = 0; j < 4; ++j) {
    lreg[j] = lrow[l4 * 4 + j];
    lreg[4 + j] = lrow[16 + l4 * 4 + j];
  }

  // ---- phase 2: write A, compute PV
  const unsigned short* Vb = V + ((size_t)b << 21) + h * 64;
  float* Ab = Aout + (((size_t)bh * 2048 + m0) << 11);
  const int wm = w >> 2, ws = w & 3;
  f32x4 pv[4];
  #pragma unroll
  for (int n = 0; n < 4; ++n) pv[n] = (f32x4){0.f, 0.f, 0.f, 0.f};

  #pragma unroll
  for (int i = 0; i < 16; ++i) {
    const int s0 = i * 128;
    {  // stage V^T tile [64 d][128 s]
      const int sl = tid >> 2, d0 = (tid & 3) * 16;
      const unsigned short* vp = Vb + ((size_t)(s0 + sl) << 10) + d0;
      uint4 v0 = *(const uint4*)vp;
      uint4 v1 = *(const uint4*)(vp + 8);
      const unsigned short* e0 = (const unsigned short*)&v0;
      const unsigned short* e1 = (const unsigned short*)&v1;
      #pragma unroll
      for (int e = 0; e < 8; ++e) u.p.vt[d0 + e][sl] = e0[e];
      #pragma unroll
      for (int e = 0; e < 8; ++e) u.p.vt[d0 + 8 + e][sl] = e1[e];
    }
    {  // probabilities -> A (f32, coalesced per row-group) + prob tile (bf16)
      const int scol = w * 16 + l15;
      #pragma unroll
      for (int j = 0; j < 4; ++j) {
        const unsigned int p = sc[i * 4 + j];
        const float a0 = __expf(bf2f(p & 0xffffu) - mreg[j]) * lreg[j];
        const float a1 = __expf(bf2f(p >> 16) - mreg[4 + j]) * lreg[4 + j];
        const int R0 = l4 * 4 + j, R1 = 16 + R0;
        Ab[((size_t)R0 << 11) + s0 + scol] = a0;
        Ab[((size_t)R1 << 11) + s0 + scol] = a1;
        u.p.prob[R0][scol] = (unsigned short)f2bf_u(a0);
        u.p.prob[R1][scol] = (unsigned short)f2bf_u(a1);
      }
    }
    __syncthreads();
    const bf16x8 pa = *(const bf16x8*)&u.p.prob[wm * 16 + l15][ws * 32 + l4 * 8];
    #pragma unroll
    for (int n = 0; n < 4; ++n) {
      const bf16x8 bv = *(const bf16x8*)&u.p.vt[n * 16 + l15][ws * 32 + l4 * 8];
      pv[n] = mfma16(pa, bv, pv[n]);
    }
    __syncthreads();
  }

  // ---- reduce PV partials across ws, write out_pre (bf16)
  #pragma unroll
  for (int n = 0; n < 4; ++n)
    #pragma unroll
    for (int q = 0; q < 4; ++q)
      u.pvred[wm][ws][l4 * 4 + q][n * 16 + l15] = pv[n][q];
  __syncthreads();
  {
    const int m = tid >> 4, d4 = (tid & 15) * 4;
    float s0 = 0.f, s1 = 0.f, s2 = 0.f, s3 = 0.f;
    #pragma unroll
    for (int w2 = 0; w2 < 4; ++w2) {
      const float* pr = &u.pvred[m >> 4][w2][m & 15][d4];
      s0 += pr[0]; s1 += pr[1]; s2 += pr[2]; s3 += pr[3];
    }
    ushort4 o;
    o.x = (unsigned short)f2bf_u(s0);
    o.y = (unsigned short)f2bf_u(s1);
    o.z = (unsigned short)f2bf_u(s2);
    o.w = (unsigned short)f2bf_u(s3);
    *(ushort4*)(OutPre + ((size_t)(b * 2048 + m0 + m) << 10) + h * 64 + d4) = o;
  }
}

// ---------------------------------------------------------------- launcher
extern "C" void kernel_launch(void* const* d_in, const int* in_sizes, int n_in,
                              void* d_out, int out_size, void* d_ws,
                              size_t ws_size, hipStream_t stream) {
  (void)in_sizes; (void)n_in; (void)out_size; (void)ws_size;
  const float* queries = (const float*)d_in[0];
  const float* keys    = (const float*)d_in[1];
  const float* values  = (const float*)d_in[2];
  const float* Wq = (const float*)d_in[3];  const float* bq = (const float*)d_in[4];
  const float* Wk = (const float*)d_in[5];  const float* bk = (const float*)d_in[6];
  const float* Wv = (const float*)d_in[7];  const float* bv = (const float*)d_in[8];
  const float* Wo = (const float*)d_in[9];  const float* bo = (const float*)d_in[10];

  float* out  = (float*)d_out;
  float* Aout = out + (size_t)2 * 2048 * 1024;  // 4,194,304 floats

  char* ws = (char*)d_ws;
  unsigned short* WqT = (unsigned short*)(ws + 0);
  unsigned short* WkT = (unsigned short*)(ws + 2097152);
  unsigned short* WvT = (unsigned short*)(ws + 4194304);
  unsigned short* WoT = (unsigned short*)(ws + 6291456);
  unsigned short* Qb  = (unsigned short*)(ws + 8388608);
  unsigned short* Kb  = (unsigned short*)(ws + 16777216);
  unsigned short* Vb  = (unsigned short*)(ws + 25165824);
  unsigned short* Op  = (unsigned short*)(ws + 33554432);  // out_pre

  transpose_w<<<dim3(32, 32, 4), dim3(32, 8), 0, stream>>>(
      Wq, Wk, Wv, Wo, WqT, WkT, WvT, WoT);

  gemm128<false, false><<<dim3(32, 8), 256, 0, stream>>>(
      queries, WqT, bq, Qb, 4096, 1024, 1024);
  gemm128<false, false><<<dim3(32, 8), 256, 0, stream>>>(
      keys, WkT, bk, Kb, 4096, 1024, 1024);
  gemm128<false, false><<<dim3(32, 8), 256, 0, stream>>>(
      values, WvT, bv, Vb, 4096, 1024, 1024);

  attn_fused<<<dim3(64, 32), 512, 0, stream>>>(Qb, Kb, Vb, Aout, Op);

  gemm128<true, true><<<dim3(32, 8), 256, 0, stream>>>(
      Op, WoT, bo, out, 4096, 1024, 1024);
}

// Round 4
// 540.413 us; speedup vs baseline: 1.0193x; 1.0193x over previous
//
#include <hip/hip_runtime.h>

// B=2, L=S=2048, D_MODEL=1024, H=16, D_HEAD=64
// d_out = [out: 2*2048*1024 f32][A: 2*16*2048*2048 f32]

typedef __attribute__((ext_vector_type(8))) __bf16 bf16x8;
typedef __attribute__((ext_vector_type(4))) float f32x4;

__device__ __forceinline__ unsigned int f2bf_u(float f) {
  unsigned int u = __float_as_uint(f);
  return (u + 0x7FFFu + ((u >> 16) & 1u)) >> 16;  // RNE
}
__device__ __forceinline__ float bf2f(unsigned int h) {
  return __uint_as_float(h << 16);
}
__device__ __forceinline__ unsigned int pack2(float lo, float hi) {
  return (f2bf_u(hi) << 16) | f2bf_u(lo);
}
__device__ __forceinline__ f32x4 mfma16(bf16x8 a, bf16x8 b, f32x4 c) {
  return __builtin_amdgcn_mfma_f32_16x16x32_bf16(a, b, c, 0, 0, 0);
}
__device__ __forceinline__ void gll16(const void* g, void* l) {
  __builtin_amdgcn_global_load_lds(
      (const __attribute__((address_space(1))) unsigned int*)g,
      (__attribute__((address_space(3))) unsigned int*)l, 16, 0, 0);
}

// ---------------------------------------------------------------- transpose
// W[1024 in][1024 out] f32  ->  WT[1024 out][1024 in] bf16
__global__ __launch_bounds__(256) void transpose_w(
    const float* __restrict__ W0, const float* __restrict__ W1,
    const float* __restrict__ W2, const float* __restrict__ W3,
    unsigned short* __restrict__ T0, unsigned short* __restrict__ T1,
    unsigned short* __restrict__ T2, unsigned short* __restrict__ T3) {
  const float* W; unsigned short* T;
  switch (blockIdx.z) {
    case 0: W = W0; T = T0; break;
    case 1: W = W1; T = T1; break;
    case 2: W = W2; T = T2; break;
    default: W = W3; T = T3; break;
  }
  __shared__ float tile[32][33];
  const int tx = threadIdx.x, ty = threadIdx.y;  // 32 x 8
  const int i0 = blockIdx.x * 32, o0 = blockIdx.y * 32;
  #pragma unroll
  for (int r = 0; r < 4; ++r)
    tile[ty + 8 * r][tx] = W[(size_t)(i0 + ty + 8 * r) * 1024 + o0 + tx];
  __syncthreads();
  #pragma unroll
  for (int r = 0; r < 4; ++r)
    T[(size_t)(o0 + ty + 8 * r) * 1024 + i0 + tx] =
        (unsigned short)f2bf_u(tile[tx][ty + 8 * r]);
}

// ---------------------------------------------------------------- GEMM 128x128
// C[M,N] = A[M,K]*BT[N,K]^T + bias
// OMODE: 0 = bf16 row-major C, 1 = f32 row-major C, 2 = bf16 transposed VT[bh][d][s]
template <bool A_BF16, int OMODE>
__global__ __launch_bounds__(256) void gemm128(
    const void* __restrict__ Ap, const unsigned short* __restrict__ BT,
    const float* __restrict__ bias, void* __restrict__ Cp,
    int M, int N, int K) {
  constexpr int AS = A_BF16 ? 32 : 40;  // pad f32-staged tile to dodge conflicts
  __shared__ unsigned short As[128][AS];
  __shared__ unsigned short Bs[128][32];
  const int tid = threadIdx.x;
  const int lane = tid & 63, wid = tid >> 6;
  const int l15 = lane & 15, l4 = lane >> 4;
  const int m0 = blockIdx.x * 128, n0 = blockIdx.y * 128;
  const int wr = wid >> 1, wc = wid & 1;

  f32x4 acc[4][4];
  #pragma unroll
  for (int i = 0; i < 4; ++i)
    #pragma unroll
    for (int j = 0; j < 4; ++j) acc[i][j] = (f32x4){0.f, 0.f, 0.f, 0.f};

  const int nk = K >> 5;
  for (int kt = 0; kt < nk; ++kt) {
    if constexpr (A_BF16) {
      const unsigned short* G = (wid < 2)
          ? ((const unsigned short*)Ap + (size_t)m0 * K)
          : (BT + (size_t)n0 * K);
      char* L = (wid < 2) ? (char*)&As[0][0] : (char*)&Bs[0][0];
      const int half = wid & 1;
      #pragma unroll
      for (int c = 0; c < 4; ++c) {
        const int off = half * 4096 + c * 1024;
        const int loff = off + lane * 16;
        const int row = loff >> 6, colb = loff & 63;
        gll16(G + (size_t)row * K + kt * 32 + colb / 2, L + off);
      }
    } else {
      if (wid < 2) {  // A f32 -> bf16, chunk-coalesced (8 rows x 128B per instr)
        #pragma unroll
        for (int c = 0; c < 8; ++c) {
          const int chunk = c * 128 + tid;
          const int row = chunk >> 3, col4 = chunk & 7;
          const float4 f = *(const float4*)((const float*)Ap +
                                            (size_t)(m0 + row) * K + kt * 32 + col4 * 4);
          ushort4 o;
          o.x = (unsigned short)f2bf_u(f.x);
          o.y = (unsigned short)f2bf_u(f.y);
          o.z = (unsigned short)f2bf_u(f.z);
          o.w = (unsigned short)f2bf_u(f.w);
          *(ushort4*)&As[row][col4 * 4] = o;
        }
      } else {
        const int half = wid & 1;
        #pragma unroll
        for (int c = 0; c < 4; ++c) {
          const int off = half * 4096 + c * 1024;
          const int loff = off + lane * 16;
          const int row = loff >> 6, colb = loff & 63;
          gll16(BT + (size_t)(n0 + row) * K + kt * 32 + colb / 2,
                (char*)&Bs[0][0] + off);
        }
      }
    }
    __syncthreads();
    bf16x8 af[4], bfr[4];
    #pragma unroll
    for (int i = 0; i < 4; ++i)
      af[i] = *(const bf16x8*)&As[wr * 64 + i * 16 + l15][l4 * 8];
    #pragma unroll
    for (int j = 0; j < 4; ++j)
      bfr[j] = *(const bf16x8*)&Bs[wc * 64 + j * 16 + l15][l4 * 8];
    #pragma unroll
    for (int i = 0; i < 4; ++i)
      #pragma unroll
      for (int j = 0; j < 4; ++j)
        acc[i][j] = mfma16(af[i], bfr[j], acc[i][j]);
    __syncthreads();
  }

  #pragma unroll
  for (int j = 0; j < 4; ++j) {
    const int col = n0 + wc * 64 + j * 16 + l15;
    const float bv = bias[col];
    #pragma unroll
    for (int i = 0; i < 4; ++i) {
      const int rowb = m0 + wr * 64 + i * 16 + l4 * 4;
      if constexpr (OMODE == 2) {
        const int bq = rowb >> 11, sq = rowb & 2047;
        const int hq = col >> 6, dq = col & 63;
        ushort4 o;
        o.x = (unsigned short)f2bf_u(acc[i][j][0] + bv);
        o.y = (unsigned short)f2bf_u(acc[i][j][1] + bv);
        o.z = (unsigned short)f2bf_u(acc[i][j][2] + bv);
        o.w = (unsigned short)f2bf_u(acc[i][j][3] + bv);
        *(ushort4*)((unsigned short*)Cp +
                    ((size_t)((bq * 16 + hq) * 64 + dq) << 11) + sq) = o;
      } else {
        #pragma unroll
        for (int q = 0; q < 4; ++q) {
          const float v = acc[i][j][q] + bv;
          if constexpr (OMODE == 1)
            ((float*)Cp)[(size_t)(rowb + q) * N + col] = v;
          else
            ((unsigned short*)Cp)[(size_t)(rowb + q) * N + col] =
                (unsigned short)f2bf_u(v);
        }
      }
    }
  }
}

// ---------------------------------------------------------------- fused attention
// grid (L/16=128, B*H=32), block 256 (4 waves). 16 q-rows/WG, s split 4 ways.
// mfma(K,Q): lane l15 = q-row -> softmax is lane-local + 2 shfl_xor.
// PV A-fragment is LANE-LOCAL: k=l4*8+j maps j=0..3 -> block 2t offs l4*4+j,
// j=4..7 -> block 2t+1 offs l4*4+j; ef = {epA[0],epA[1],epB[0],epB[1]}.
// Matching V B-frag: two 8B loads at s-base and s-base+64.
__global__ __launch_bounds__(256) void attn_fused(
    const unsigned short* __restrict__ Q, const unsigned short* __restrict__ K,
    const unsigned short* __restrict__ VT, float* __restrict__ Aout,
    unsigned short* __restrict__ OutPre) {
  __shared__ float stats[4][16];
  __shared__ float mrow[16];
  __shared__ float lrow[16];
  __shared__ float red[4][16][68];

  const int tid = threadIdx.x;
  const int w = tid >> 6, lane = tid & 63;
  const int l15 = lane & 15, l4 = lane >> 4;
  const int bh = blockIdx.y, b = bh >> 4, h = bh & 15;
  const int m0 = blockIdx.x * 16;

  // Q fragment (B-operand: lane l15 = q-row m, k-chunk = l4*8)
  const unsigned short* Qp =
      Q + ((size_t)(b * 2048 + m0 + l15) << 10) + h * 64 + l4 * 8;
  const bf16x8 qf0 = *(const bf16x8*)Qp;
  const bf16x8 qf1 = *(const bf16x8*)(Qp + 32);

  const unsigned short* Kb = K + ((size_t)b << 21) + h * 64;
  unsigned int sc[64];  // packed bf16 scaled scores, j-pairs
  float rmax = -3.0e38f;

  // ---- phase 1: scores^T = K·Q^T ; D[s'][m]: col=l15=m, row=l4*4+j -> s-offset
  #pragma unroll
  for (int i = 0; i < 32; ++i) {
    const unsigned short* kp = Kb + ((size_t)(i * 64 + w * 16 + l15) << 10) + l4 * 8;
    const bf16x8 k0 = *(const bf16x8*)kp;
    const bf16x8 k1 = *(const bf16x8*)(kp + 32);
    f32x4 a = {0.f, 0.f, 0.f, 0.f};
    a = mfma16(k0, qf0, a);
    a = mfma16(k1, qf1, a);
    const float s0 = a[0] * 0.125f, s1 = a[1] * 0.125f;
    const float s2 = a[2] * 0.125f, s3 = a[3] * 0.125f;
    rmax = fmaxf(rmax, fmaxf(fmaxf(s0, s1), fmaxf(s2, s3)));
    sc[i * 2 + 0] = pack2(s0, s1);
    sc[i * 2 + 1] = pack2(s2, s3);
  }
  rmax = fmaxf(rmax, __shfl_xor(rmax, 16));
  rmax = fmaxf(rmax, __shfl_xor(rmax, 32));
  if (lane < 16) stats[w][l15] = rmax;
  __syncthreads();
  if (tid < 16)
    mrow[tid] = fmaxf(fmaxf(stats[0][tid], stats[1][tid]),
                      fmaxf(stats[2][tid], stats[3][tid]));
  __syncthreads();
  const float mreg = mrow[l15];

  float lsum = 0.f;
  #pragma unroll
  for (int r = 0; r < 64; ++r) {
    const unsigned int p = sc[r];
    lsum += __expf(bf2f(p & 0xffffu) - mreg) + __expf(bf2f(p >> 16) - mreg);
  }
  lsum += __shfl_xor(lsum, 16);
  lsum += __shfl_xor(lsum, 32);
  if (lane < 16) stats[w][l15] = lsum;
  __syncthreads();
  if (tid < 16)
    lrow[tid] = 1.0f / (stats[0][tid] + stats[1][tid] + stats[2][tid] + stats[3][tid]);
  __syncthreads();
  const float lreg = lrow[l15];

  // ---- phase 2: A-write + PV, no barriers, no shuffles
  const unsigned short* Vb = VT + ((size_t)bh << 17);  // [64 d][2048 s]
  float* Ab = Aout + ((size_t)bh << 22) + ((size_t)(m0 + l15) << 11) + w * 16 + l4 * 4;
  f32x4 pv[4];
  #pragma unroll
  for (int nt = 0; nt < 4; ++nt) pv[nt] = (f32x4){0.f, 0.f, 0.f, 0.f};

  #pragma unroll
  for (int t = 0; t < 16; ++t) {
    unsigned int epA[2], epB[2];
    {
      const unsigned int p0 = sc[4 * t + 0], p1 = sc[4 * t + 1];
      const float e0 = __expf(bf2f(p0 & 0xffffu) - mreg);
      const float e1 = __expf(bf2f(p0 >> 16) - mreg);
      const float e2 = __expf(bf2f(p1 & 0xffffu) - mreg);
      const float e3 = __expf(bf2f(p1 >> 16) - mreg);
      const f32x4 av = {e0 * lreg, e1 * lreg, e2 * lreg, e3 * lreg};
      __builtin_nontemporal_store(av, (f32x4*)(Ab + (2 * t) * 64));
      epA[0] = pack2(e0, e1);
      epA[1] = pack2(e2, e3);
    }
    {
      const unsigned int p0 = sc[4 * t + 2], p1 = sc[4 * t + 3];
      const float e0 = __expf(bf2f(p0 & 0xffffu) - mreg);
      const float e1 = __expf(bf2f(p0 >> 16) - mreg);
      const float e2 = __expf(bf2f(p1 & 0xffffu) - mreg);
      const float e3 = __expf(bf2f(p1 >> 16) - mreg);
      const f32x4 av = {e0 * lreg, e1 * lreg, e2 * lreg, e3 * lreg};
      __builtin_nontemporal_store(av, (f32x4*)(Ab + (2 * t + 1) * 64));
      epB[0] = pack2(e0, e1);
      epB[1] = pack2(e2, e3);
    }
    // A-operand fragment: lane-local (k = l4*8+j ; j<4 -> block 2t, j>=4 -> 2t+1)
    union { unsigned int u[4]; bf16x8 v; } ef;
    ef.u[0] = epA[0]; ef.u[1] = epA[1];
    ef.u[2] = epB[0]; ef.u[3] = epB[1];
    const unsigned short* vtp = Vb + (size_t)l15 * 2048 + t * 128 + w * 16 + l4 * 4;
    #pragma unroll
    for (int nt = 0; nt < 4; ++nt) {
      const unsigned short* pp = vtp + (size_t)(nt * 16) * 2048;
      union { unsigned int u[4]; bf16x8 v; } vf;
      const uint2 va = *(const uint2*)pp;         // block 2t   : offs l4*4+0..3
      const uint2 vb = *(const uint2*)(pp + 64);  // block 2t+1 : offs l4*4+0..3
      vf.u[0] = va.x; vf.u[1] = va.y; vf.u[2] = vb.x; vf.u[3] = vb.y;
      pv[nt] = mfma16(ef.v, vf.v, pv[nt]);
    }
  }

  // ---- cross-wave PV reduce (once), scale by 1/l, write out_pre
  #pragma unroll
  for (int nt = 0; nt < 4; ++nt)
    #pragma unroll
    for (int q = 0; q < 4; ++q)
      red[w][l4 * 4 + q][nt * 16 + l15] = pv[nt][q];
  __syncthreads();
  {
    const int m = tid >> 4, d4 = (tid & 15) * 4;
    float4 s = {0.f, 0.f, 0.f, 0.f};
    #pragma unroll
    for (int ww = 0; ww < 4; ++ww) {
      const float4 pr = *(const float4*)&red[ww][m][d4];
      s.x += pr.x; s.y += pr.y; s.z += pr.z; s.w += pr.w;
    }
    const float li = lrow[m];
    ushort4 o;
    o.x = (unsigned short)f2bf_u(s.x * li);
    o.y = (unsigned short)f2bf_u(s.y * li);
    o.z = (unsigned short)f2bf_u(s.z * li);
    o.w = (unsigned short)f2bf_u(s.w * li);
    *(ushort4*)(OutPre + ((size_t)(b * 2048 + m0 + m) << 10) + h * 64 + d4) = o;
  }
}

// ---------------------------------------------------------------- launcher
extern "C" void kernel_launch(void* const* d_in, const int* in_sizes, int n_in,
                              void* d_out, int out_size, void* d_ws,
                              size_t ws_size, hipStream_t stream) {
  (void)in_sizes; (void)n_in; (void)out_size; (void)ws_size;
  const float* queries = (const float*)d_in[0];
  const float* keys    = (const float*)d_in[1];
  const float* values  = (const float*)d_in[2];
  const float* Wq = (const float*)d_in[3];  const float* bq = (const float*)d_in[4];
  const float* Wk = (const float*)d_in[5];  const float* bk = (const float*)d_in[6];
  const float* Wv = (const float*)d_in[7];  const float* bv = (const float*)d_in[8];
  const float* Wo = (const float*)d_in[9];  const float* bo = (const float*)d_in[10];

  float* out  = (float*)d_out;
  float* Aout = out + (size_t)2 * 2048 * 1024;

  char* ws = (char*)d_ws;
  unsigned short* WqT = (unsigned short*)(ws + 0);
  unsigned short* WkT = (unsigned short*)(ws + 2097152);
  unsigned short* WvT = (unsigned short*)(ws + 4194304);
  unsigned short* WoT = (unsigned short*)(ws + 6291456);
  unsigned short* Qb  = (unsigned short*)(ws + 8388608);
  unsigned short* Kb  = (unsigned short*)(ws + 16777216);
  unsigned short* VTb = (unsigned short*)(ws + 25165824);  // [bh][64][2048]
  unsigned short* Op  = (unsigned short*)(ws + 33554432);  // out_pre bf16

  transpose_w<<<dim3(32, 32, 4), dim3(32, 8), 0, stream>>>(
      Wq, Wk, Wv, Wo, WqT, WkT, WvT, WoT);

  gemm128<false, 0><<<dim3(32, 8), 256, 0, stream>>>(
      queries, WqT, bq, Qb, 4096, 1024, 1024);
  gemm128<false, 0><<<dim3(32, 8), 256, 0, stream>>>(
      keys, WkT, bk, Kb, 4096, 1024, 1024);
  gemm128<false, 2><<<dim3(32, 8), 256, 0, stream>>>(
      values, WvT, bv, VTb, 4096, 1024, 1024);

  attn_fused<<<dim3(128, 32), 256, 0, stream>>>(Qb, Kb, VTb, Aout, Op);

  gemm128<true, 1><<<dim3(32, 8), 256, 0, stream>>>(
      Op, WoT, bo, out, 4096, 1024, 1024);
}